// Round 1
// baseline (1947.806 us; speedup 1.0000x reference)
//
#include <hip/hip_runtime.h>
#include <hip/hip_bf16.h>
#include <cstdint>

// CapsuleLayer dynamic routing, MI355X.
// B=16, N=64, I=2048, D=32, E=16, ROUTINGS=3.
// b_k = (sum_j v_j) . u_hat  (b starts at 0, all updates are v.u_hat) -> never
// materialize b or u_hat; 3 streaming passes over W (256MB each), fused
// routing per pass. s-accumulator lives in d_out; only vtot (128KB) in d_ws.

#define B_ 16
#define N_ 64
#define I_ 2048
#define D_ 32
#define E_ 16
#define NT_ (B_ * N_)   // 1024 threads per block: thread t <-> (n = t>>4, b = t&15)
#define EPS_ 1e-7f

// MODE 0: c = 1/64 (softmax of zero logits), vtot unused.
// MODE 1: logits = vtot . u_hat, softmax over n (within block), c applied.
template <int MODE>
__global__ __launch_bounds__(NT_) void caps_pass(
    const float* __restrict__ W,     // [N][I][D][E]
    const float* __restrict__ x,     // [B][I][E]
    const float* __restrict__ vtot,  // [t=(n*16+b)][D]  (thread-order layout)
    float* __restrict__ s_out,       // [t][D] accumulated via atomics (pre-zeroed)
    int iPer)
{
  const int t = threadIdx.x;
  const int n = t >> 4;
  const int b = t & 15;

  __shared__ float x_lds[B_ * E_];     // x[:, i, :]
  __shared__ float l_lds[N_ * 17];     // padded logits for conflict-free transpose
  __shared__ float m_lds[B_], d_lds[B_];

  float acc[D_];
#pragma unroll
  for (int d = 0; d < D_; ++d) acc[d] = 0.f;

  const int i0 = blockIdx.x * iPer;
  for (int ii = 0; ii < iPer; ++ii) {
    const int i = i0 + ii;

    __syncthreads();  // protect x_lds / l_lds reuse from previous iteration
    if (t < B_ * E_) {
      const int bb = t >> 4, e = t & 15;
      x_lds[t] = x[(size_t)bb * (I_ * E_) + (size_t)i * E_ + e];
    }
    __syncthreads();

    const float4 xv0 = *(const float4*)&x_lds[b * E_ + 0];
    const float4 xv1 = *(const float4*)&x_lds[b * E_ + 4];
    const float4 xv2 = *(const float4*)&x_lds[b * E_ + 8];
    const float4 xv3 = *(const float4*)&x_lds[b * E_ + 12];

    // u_hat[b,n,i,d] = sum_e W[n,i,d,e] * x[b,i,e]
    const float* Wp = W + ((size_t)n * I_ + (size_t)i) * (D_ * E_);
    float uh[D_];
#pragma unroll
    for (int d = 0; d < D_; ++d) {
      const float4 w0 = *(const float4*)&Wp[d * E_ + 0];
      const float4 w1 = *(const float4*)&Wp[d * E_ + 4];
      const float4 w2 = *(const float4*)&Wp[d * E_ + 8];
      const float4 w3 = *(const float4*)&Wp[d * E_ + 12];
      float s = w0.x * xv0.x + w0.y * xv0.y + w0.z * xv0.z + w0.w * xv0.w;
      s += w1.x * xv1.x + w1.y * xv1.y + w1.z * xv1.z + w1.w * xv1.w;
      s += w2.x * xv2.x + w2.y * xv2.y + w2.z * xv2.z + w2.w * xv2.w;
      s += w3.x * xv3.x + w3.y * xv3.y + w3.z * xv3.z + w3.w * xv3.w;
      uh[d] = s;
    }

    float c;
    if (MODE == 0) {
      c = 1.0f / 64.0f;
    } else {
      // logit l[b,n,i] = sum_d vtot[b,n,d] * uh[d]
      float l = 0.f;
      const float* vp = vtot + (size_t)t * D_;
#pragma unroll
      for (int d4 = 0; d4 < 8; ++d4) {
        const float4 v4 = *(const float4*)&vp[d4 * 4];
        l += v4.x * uh[d4 * 4 + 0] + v4.y * uh[d4 * 4 + 1] +
             v4.z * uh[d4 * 4 + 2] + v4.w * uh[d4 * 4 + 3];
      }
      // softmax over n for fixed b. 64 n-values for one b are scattered across
      // waves; transpose via LDS so wave w holds row b=w, then shuffle-reduce.
      l_lds[n * 17 + b] = l;
      __syncthreads();
      {
        const int w = t >> 6, j = t & 63;  // wave w <-> b=w, lane j <-> n=j
        const float val = l_lds[j * 17 + w];
        float m = val;
#pragma unroll
        for (int off = 32; off; off >>= 1) m = fmaxf(m, __shfl_xor(m, off));
        float e = __expf(val - m);
#pragma unroll
        for (int off = 32; off; off >>= 1) e += __shfl_xor(e, off);
        if (j == 0) { m_lds[w] = m; d_lds[w] = e; }
      }
      __syncthreads();
      c = __expf(l - m_lds[b]) / d_lds[b];
    }

#pragma unroll
    for (int d = 0; d < D_; ++d) acc[d] += c * uh[d];
  }

#pragma unroll
  for (int d = 0; d < D_; ++d) atomicAdd(&s_out[(size_t)t * D_ + d], acc[d]);
}

// vtot[t*D+d] += squash(s_in[t])[d]   (grid-strided over the 1024 rows)
__global__ void caps_squash_acc(const float* __restrict__ s_in,
                                float* __restrict__ vtot)
{
  const int t = blockIdx.x * blockDim.x + threadIdx.x;
  if (t >= NT_) return;
  float v[D_];
  float s2 = 0.f;
#pragma unroll
  for (int d = 0; d < D_; ++d) {
    v[d] = s_in[(size_t)t * D_ + d];
    s2 += v[d] * v[d];
  }
  const float f = s2 / ((1.f + s2) * sqrtf(s2 + EPS_));
#pragma unroll
  for (int d = 0; d < D_; ++d) vtot[(size_t)t * D_ + d] += v[d] * f;
}

// In-place final squash + permute thread-order [t=(n*16+b)][d] -> [b][n][d].
// Single 1024-thread block: read all rows into regs, barrier, write permuted.
__global__ __launch_bounds__(NT_) void caps_squash_final(float* __restrict__ s_io)
{
  const int t = threadIdx.x;
  float v[D_];
  float s2 = 0.f;
#pragma unroll
  for (int d = 0; d < D_; ++d) {
    v[d] = s_io[(size_t)t * D_ + d];
    s2 += v[d] * v[d];
  }
  const float f = s2 / ((1.f + s2) * sqrtf(s2 + EPS_));
  __syncthreads();  // all reads done before any permuted write
  const int n = t >> 4, b = t & 15;
#pragma unroll
  for (int d = 0; d < D_; ++d)
    s_io[(size_t)b * (N_ * D_) + (size_t)n * D_ + d] = v[d] * f;
}

extern "C" void kernel_launch(void* const* d_in, const int* in_sizes, int n_in,
                              void* d_out, int out_size, void* d_ws, size_t ws_size,
                              hipStream_t stream)
{
  const float* x = (const float*)d_in[0];  // [16][2048][16]
  const float* W = (const float*)d_in[1];  // [64][2048][32][16]
  float* s_acc = (float*)d_out;            // 32768 floats, reused as accumulator
  float* vtot  = (float*)d_ws;             // 32768 floats (128 KB)

  const size_t sbytes = (size_t)NT_ * D_ * sizeof(float);
  const int grid = 256;
  const int iPer = I_ / grid;  // 8

  hipMemsetAsync(s_acc, 0, sbytes, stream);
  hipMemsetAsync(vtot, 0, sbytes, stream);

  // Round 1: c = 1/64, s0 = (1/64) sum_i u_hat  -> v0
  caps_pass<0><<<grid, NT_, 0, stream>>>(W, x, nullptr, s_acc, iPer);
  caps_squash_acc<<<4, 256, 0, stream>>>(s_acc, vtot);  // vtot = v0

  // Round 2: logits = v0 . u_hat
  hipMemsetAsync(s_acc, 0, sbytes, stream);
  caps_pass<1><<<grid, NT_, 0, stream>>>(W, x, vtot, s_acc, iPer);
  caps_squash_acc<<<4, 256, 0, stream>>>(s_acc, vtot);  // vtot = v0 + v1

  // Round 3: logits = (v0+v1) . u_hat  -> final squash into [b][n][d]
  hipMemsetAsync(s_acc, 0, sbytes, stream);
  caps_pass<1><<<grid, NT_, 0, stream>>>(W, x, vtot, s_acc, iPer);
  caps_squash_final<<<1, NT_, 0, stream>>>(s_acc);
}

// Round 2
// 858.246 us; speedup vs baseline: 2.2695x; 2.2695x over previous
//
#include <hip/hip_runtime.h>
#include <cstdint>

// CapsuleLayer dynamic routing, MI355X. B=16,N=64,I=2048,D=32,E=16,R=3.
// b-logits = (sum_j v_j).u_hat -> never materialize b or u_hat; 3 streaming
// passes over W (256MB each). Wave = one (n,i) tile: coalesced 1KB W loads,
// DPP quad_perm reduce-scatter over e-quarters (VALU pipe, no ds_swizzle),
// x/v read via global (L1/L2), per-block non-atomic partials in d_ws
// (atomic fallback if ws too small).

#define B_ 16
#define N_ 64
#define I_ 2048
#define D_ 32
#define E_ 16
#define EPS_ 1e-7f
#define IPER_ 8
#define GRID_ 256
#define SROW_ 2048          // b-stride in s = N_*D_
#define NOUT_ 32768         // B_*N_*D_
#define PSTRIDE_ 32768      // floats per block partial

template <int CTRL>
__device__ __forceinline__ float dppf(float v) {
  return __int_as_float(
      __builtin_amdgcn_update_dpp(0, __float_as_int(v), CTRL, 0xF, 0xF, true));
}
// DPP ctrl: quad_perm[1,0,3,2]=0xB1 (xor1), quad_perm[2,3,0,1]=0x4E (xor2),
// row_ror:4=0x124, row_ror:8=0x128 (rows = 16 lanes).

// MODE 0: c = 1/64 (softmax of zero logits), no barriers in i-loop.
// MODE 1: logits = vtot . u_hat, softmax over n within block.
template <int MODE>
__global__ __launch_bounds__(1024) void caps_pass(
    const float* __restrict__ W,     // [N][I][D][E]
    const float* __restrict__ x,     // [B][I][E]
    const float* __restrict__ vtot,  // [B][N][D]
    float* __restrict__ out,         // partials base or s (atomic)
    int use_part)
{
  const int t = threadIdx.x;
  const int w = t >> 6;      // wave 0..15 -> n = 4w+nn
  const int l = t & 63;
  const int q = l & 3;       // e-quarter
  const int dd = l >> 2;     // d (0..15); also owns d+16

  __shared__ float l2[N_ * 65];      // logit row-partials [n][b][row4], pad
  __shared__ float c_lds[N_ * 17];   // c [n][b], pad

  float acc0[4][4], acc1[4][4];      // [nn][k], b=4k+q, d=dd / dd+16
  float u0a[4][4], u1a[4][4];        // MODE1: u_hat kept across softmax
#pragma unroll
  for (int nn = 0; nn < 4; ++nn)
#pragma unroll
    for (int k = 0; k < 4; ++k) { acc0[nn][k] = 0.f; acc1[nn][k] = 0.f; }

  const int i0 = blockIdx.x * IPER_;
  for (int ii = 0; ii < IPER_; ++ii) {
    const int i = i0 + ii;
    // x[b,i,4q..4q+3] as float4: index b*8192 + i*4 + q
    const float4* xg = (const float4*)x + (size_t)i * 4 + q;

    // preload W for nn=0 (1KB unique per wave-instr, fully coalesced)
    const float4* Wf0 = (const float4*)(W + (((size_t)(4 * w) * I_ + i) << 9));
    float4 wa0 = Wf0[l], wa1 = Wf0[64 + l];

#pragma unroll
    for (int nn = 0; nn < 4; ++nn) {
      const int n = 4 * w + nn;
      float4 wb0, wb1;
      if (nn < 3) {
        const float4* Wn = (const float4*)(W + (((size_t)(n + 1) * I_ + i) << 9));
        wb0 = Wn[l]; wb1 = Wn[64 + l];
      }

      float p0[16], p1[16];
#pragma unroll
      for (int b = 0; b < 16; ++b) {
        const float4 xv = xg[(size_t)b * 8192];
        p0[b] = wa0.x * xv.x + wa0.y * xv.y + wa0.z * xv.z + wa0.w * xv.w;
        p1[b] = wa1.x * xv.x + wa1.y * xv.y + wa1.z * xv.z + wa1.w * xv.w;
      }

      // reduce-scatter over the quad (e-quarters); static regs + cndmask.
      float u0[4], u1[4];
      {
        float r1[8];
#pragma unroll
        for (int j = 0; j < 8; ++j) {
          const float a0 = p0[2 * j] + dppf<0xB1>(p0[2 * j]);
          const float a1 = p0[2 * j + 1] + dppf<0xB1>(p0[2 * j + 1]);
          r1[j] = (q & 1) ? a1 : a0;           // holds b = 2j + (q&1)
        }
#pragma unroll
        for (int k = 0; k < 4; ++k) {
          const float a0 = r1[2 * k] + dppf<0x4E>(r1[2 * k]);
          const float a1 = r1[2 * k + 1] + dppf<0x4E>(r1[2 * k + 1]);
          u0[k] = (q & 2) ? a1 : a0;           // full sum, b = 4k + q
        }
      }
      {
        float r1[8];
#pragma unroll
        for (int j = 0; j < 8; ++j) {
          const float a0 = p1[2 * j] + dppf<0xB1>(p1[2 * j]);
          const float a1 = p1[2 * j + 1] + dppf<0xB1>(p1[2 * j + 1]);
          r1[j] = (q & 1) ? a1 : a0;
        }
#pragma unroll
        for (int k = 0; k < 4; ++k) {
          const float a0 = r1[2 * k] + dppf<0x4E>(r1[2 * k]);
          const float a1 = r1[2 * k + 1] + dppf<0x4E>(r1[2 * k + 1]);
          u1[k] = (q & 2) ? a1 : a0;
        }
      }

      if (MODE == 0) {
#pragma unroll
        for (int k = 0; k < 4; ++k) {
          acc0[nn][k] += u0[k];
          acc1[nn][k] += u1[k];
        }
      } else {
#pragma unroll
        for (int k = 0; k < 4; ++k) { u0a[nn][k] = u0[k]; u1a[nn][k] = u1[k]; }
        // logit partial over this lane's two d's, then ror-reduce over dd
#pragma unroll
        for (int k = 0; k < 4; ++k) {
          const int b = 4 * k + q;
          const size_t va = (size_t)b * SROW_ + (size_t)n * D_ + dd;
          float lp = vtot[va] * u0[k] + vtot[va + 16] * u1[k];
          lp += dppf<0x124>(lp);   // + ror4  (same q preserved)
          lp += dppf<0x128>(lp);   // + ror8 -> sum over row's 4 dd
          if ((l & 12) == 0)       // one writer per (row, q)
            l2[n * 65 + b * 4 + (l >> 4)] = lp;
        }
      }
      if (nn < 3) { wa0 = wb0; wa1 = wb1; }
    }

    if (MODE == 1) {
      __syncthreads();
      {
        // wave bw handles b=bw, lane j = n
        const int bw = t >> 6, j = t & 63;
        const int base = j * 65 + bw * 4;
        const float raw = l2[base] + l2[base + 1] + l2[base + 2] + l2[base + 3];
        float m = raw;
#pragma unroll
        for (int off = 32; off; off >>= 1) m = fmaxf(m, __shfl_xor(m, off));
        float e = __expf(raw - m);
        float den = e;
#pragma unroll
        for (int off = 32; off; off >>= 1) den += __shfl_xor(den, off);
        c_lds[j * 17 + bw] = e / den;
      }
      __syncthreads();
#pragma unroll
      for (int nn = 0; nn < 4; ++nn) {
#pragma unroll
        for (int k = 0; k < 4; ++k) {
          const float cc = c_lds[(4 * w + nn) * 17 + 4 * k + q];
          acc0[nn][k] += cc * u0a[nn][k];
          acc1[nn][k] += cc * u1a[nn][k];
        }
      }
    }
  }

  // store: partial slice (non-atomic) or atomic accumulate
  const float sc = (MODE == 0) ? (1.f / 64.f) : 1.f;
  float* base = out + (use_part ? (size_t)blockIdx.x * PSTRIDE_ : 0);
#pragma unroll
  for (int nn = 0; nn < 4; ++nn) {
#pragma unroll
    for (int k = 0; k < 4; ++k) {
      const int b = 4 * k + q, n = 4 * w + nn;
      const size_t a = (size_t)b * SROW_ + (size_t)n * D_ + dd;
      if (use_part) {
        base[a] = acc0[nn][k] * sc;
        base[a + 16] = acc1[nn][k] * sc;
      } else {
        atomicAdd(&base[a], acc0[nn][k] * sc);
        atomicAdd(&base[a + 16], acc1[nn][k] * sc);
      }
    }
  }
}

__global__ void reduce_partials(const float* __restrict__ part,
                                float* __restrict__ s)
{
  const int t = blockIdx.x * blockDim.x + threadIdx.x;  // 32768 threads
  float sum = 0.f;
#pragma unroll 4
  for (int b = 0; b < GRID_; ++b) sum += part[(size_t)b * PSTRIDE_ + t];
  s[t] = sum;
}

// vtot[row] += squash(s[row]); rows are (b*64+n), 32 floats each
__global__ void caps_squash_acc(const float* __restrict__ s_in,
                                float* __restrict__ vtot)
{
  const int t = blockIdx.x * blockDim.x + threadIdx.x;
  if (t >= B_ * N_) return;
  float v[D_];
  float s2 = 0.f;
#pragma unroll
  for (int d = 0; d < D_; ++d) {
    v[d] = s_in[(size_t)t * D_ + d];
    s2 += v[d] * v[d];
  }
  const float f = s2 / ((1.f + s2) * sqrtf(s2 + EPS_));
#pragma unroll
  for (int d = 0; d < D_; ++d) vtot[(size_t)t * D_ + d] += v[d] * f;
}

__global__ void caps_squash_final(float* __restrict__ s_io)
{
  const int t = blockIdx.x * blockDim.x + threadIdx.x;
  if (t >= B_ * N_) return;
  float v[D_];
  float s2 = 0.f;
#pragma unroll
  for (int d = 0; d < D_; ++d) {
    v[d] = s_io[(size_t)t * D_ + d];
    s2 += v[d] * v[d];
  }
  const float f = s2 / ((1.f + s2) * sqrtf(s2 + EPS_));
#pragma unroll
  for (int d = 0; d < D_; ++d) s_io[(size_t)t * D_ + d] = v[d] * f;
}

extern "C" void kernel_launch(void* const* d_in, const int* in_sizes, int n_in,
                              void* d_out, int out_size, void* d_ws, size_t ws_size,
                              hipStream_t stream)
{
  const float* x = (const float*)d_in[0];  // [16][2048][16]
  const float* W = (const float*)d_in[1];  // [64][2048][32][16]
  float* s = (float*)d_out;                // [b][n][d] accumulator / output
  float* vtot = (float*)d_ws;              // 32768 floats
  float* part = vtot + NOUT_;              // 256 * 32768 floats if available

  const size_t need = ((size_t)NOUT_ + (size_t)GRID_ * PSTRIDE_) * sizeof(float);
  const int use_part = (ws_size >= need) ? 1 : 0;
  float* pass_out = use_part ? part : s;

  const size_t sbytes = (size_t)NOUT_ * sizeof(float);
  hipMemsetAsync(vtot, 0, sbytes, stream);

  // Round 1: c = 1/64
  if (!use_part) hipMemsetAsync(s, 0, sbytes, stream);
  caps_pass<0><<<GRID_, 1024, 0, stream>>>(W, x, vtot, pass_out, use_part);
  if (use_part) reduce_partials<<<128, 256, 0, stream>>>(part, s);
  caps_squash_acc<<<4, 256, 0, stream>>>(s, vtot);          // vtot = v0

  // Round 2: logits = v0 . u_hat
  if (!use_part) hipMemsetAsync(s, 0, sbytes, stream);
  caps_pass<1><<<GRID_, 1024, 0, stream>>>(W, x, vtot, pass_out, use_part);
  if (use_part) reduce_partials<<<128, 256, 0, stream>>>(part, s);
  caps_squash_acc<<<4, 256, 0, stream>>>(s, vtot);          // vtot = v0+v1

  // Round 3: logits = (v0+v1) . u_hat -> final squash in place
  if (!use_part) hipMemsetAsync(s, 0, sbytes, stream);
  caps_pass<1><<<GRID_, 1024, 0, stream>>>(W, x, vtot, pass_out, use_part);
  if (use_part) reduce_partials<<<128, 256, 0, stream>>>(part, s);
  caps_squash_final<<<4, 256, 0, stream>>>(s);
}